// Round 12
// baseline (797.153 us; speedup 1.0000x reference)
//
#include <hip/hip_runtime.h>

typedef short short8 __attribute__((ext_vector_type(8)));
typedef __bf16 bf16x8 __attribute__((ext_vector_type(8)));
typedef float f32x4 __attribute__((ext_vector_type(4)));
typedef unsigned long long u64;

#define FEAT 128
#define FPL 2048
#define LOG2E 1.4426950408889634f

__device__ __forceinline__ float b2f(unsigned int u) {
  union { unsigned int u; float f; } c; c.u = u << 16; return c.f;
}
__device__ __forceinline__ unsigned short f2b(float f) {
  union { float f; unsigned int u; } c; c.f = f;
  unsigned int r = c.u + 0x7fffu + ((c.u >> 16) & 1u);
  return (unsigned short)(r >> 16);
}
__device__ __forceinline__ f32x4 mfma16(short8 a, short8 b, f32x4 c) {
  return __builtin_amdgcn_mfma_f32_16x16x32_bf16(
      __builtin_bit_cast(bf16x8, a), __builtin_bit_cast(bf16x8, b), c, 0, 0, 0);
}
__device__ __forceinline__ float exp2x(float x) {
  float r; asm("v_exp_f32 %0, %1" : "=v"(r) : "v"(x)); return r;
}
__device__ __forceinline__ void add8(float* a, ulonglong2 v) {
  u64 lo = v.x, hi = v.y;
  a[0] += b2f((unsigned int)(lo & 0xffffu));
  a[1] += b2f((unsigned int)((lo >> 16) & 0xffffu));
  a[2] += b2f((unsigned int)((lo >> 32) & 0xffffu));
  a[3] += b2f((unsigned int)(lo >> 48));
  a[4] += b2f((unsigned int)(hi & 0xffffu));
  a[5] += b2f((unsigned int)((hi >> 16) & 0xffffu));
  a[6] += b2f((unsigned int)((hi >> 32) & 0xffffu));
  a[7] += b2f((unsigned int)(hi >> 48));
}

// ---- conversion kernels ----
__global__ void cvt_kernel(const float* __restrict__ in, unsigned short* __restrict__ out, int n2) {
  int i = blockIdx.x * 256 + threadIdx.x;
  if (i < n2) {
    float2 v = ((const float2*)in)[i];
    unsigned int lo = f2b(v.x), hi = f2b(v.y);
    ((unsigned int*)out)[i] = lo | (hi << 16);
  }
}

__global__ void cvtT_kernel(const float* __restrict__ W, unsigned short* __restrict__ WT,
                            int K, int N, float scale) {
  int i = blockIdx.x * 256 + threadIdx.x;
  if (i < K * N) {
    int k = i / N, c = i - k * N;
    WT[(size_t)c * K + k] = f2b(W[i] * scale);
  }
}

// ---- CSR build ----
__global__ void count_kernel(const int* __restrict__ dst, int* __restrict__ cnt, int n) {
  int i = blockIdx.x * 256 + threadIdx.x;
  if (i < n) atomicAdd(&cnt[dst[i]], 1);
}

__global__ __launch_bounds__(1024) void scan1_kernel(const int* __restrict__ cnt,
    int* __restrict__ ex, int* __restrict__ chunkSum, int n) {
  __shared__ int sd[1024];
  const int i = blockIdx.x * 1024 + threadIdx.x;
  int v = (i < n) ? cnt[i] : 0;
  sd[threadIdx.x] = v;
  __syncthreads();
  int sum = v;
  for (int off = 1; off < 1024; off <<= 1) {
    int t = (threadIdx.x >= (unsigned)off) ? sd[threadIdx.x - off] : 0;
    __syncthreads();
    sum += t;
    sd[threadIdx.x] = sum;
    __syncthreads();
  }
  if (i < n) ex[i] = sum - v;
  if (threadIdx.x == 1023) chunkSum[blockIdx.x] = sum;
}

__global__ __launch_bounds__(1024) void scan2_kernel(const int* __restrict__ chunkSum,
    int* __restrict__ chunkOff, int nChunks) {
  __shared__ int sd[1024];
  int v = (threadIdx.x < (unsigned)nChunks) ? chunkSum[threadIdx.x] : 0;
  sd[threadIdx.x] = v;
  __syncthreads();
  int sum = v;
  for (int off = 1; off < 1024; off <<= 1) {
    int t = (threadIdx.x >= (unsigned)off) ? sd[threadIdx.x - off] : 0;
    __syncthreads();
    sum += t;
    sd[threadIdx.x] = sum;
    __syncthreads();
  }
  if (threadIdx.x < (unsigned)nChunks) chunkOff[threadIdx.x] = sum - v;
}

__global__ void scan3_kernel(const int* __restrict__ ex, const int* __restrict__ chunkOff,
    const int* __restrict__ chunkSum, int* __restrict__ rp, int n, int nChunks) {
  int i = blockIdx.x * 256 + threadIdx.x;
  if (i < n) rp[i] = ex[i] + chunkOff[i >> 10];
  if (i == 0) rp[n] = chunkOff[nChunks - 1] + chunkSum[nChunks - 1];
}

__global__ void copy_kernel(const int* __restrict__ a, int* __restrict__ b, int n) {
  int i = blockIdx.x * 256 + threadIdx.x;
  if (i < n) b[i] = a[i];
}

// XCD-partitioned CSR fill, v2. Round-11 counters (WRITE still 61 MB) proved
// the blockIdx%8->XCD guess wrong: partition p's col lines were still dirtied
// across multiple XCD L2s. Now each block reads its REAL XCD id from
// HW_REG_XCC_ID (hwreg id 20, returns 0-7 on MI355X [learn_hip m09]) and
// serves only that XCD's contiguous dst-slice -> col/cursor lines live in
// exactly one L2, written back once. Per-partition work distribution via 8
// atomic chunk counters (blocks-per-XCD is unknown at dispatch). Plain loads
// (no nontemporal): L3 serves the 8x dst re-stream.
#define FILL_CHUNK 8192
__global__ __launch_bounds__(256) void fillx_kernel(const int* __restrict__ src,
    const int* __restrict__ dst, int* __restrict__ cursor, int* __restrict__ col,
    int* __restrict__ work, int n, int nAtoms) {
  unsigned int xcc;
  asm volatile("s_getreg_b32 %0, hwreg(20, 0, 32)" : "=s"(xcc));  // HW_REG_XCC_ID
  const int part = (int)(xcc & 7u);
  const int partSize = (nAtoms + 7) >> 3;
  const int lo = part * partSize;
  const int hi = min(lo + partSize, nAtoms);
  __shared__ int base;
  for (;;) {
    if (threadIdx.x == 0) base = atomicAdd(&work[part], FILL_CHUNK);
    __syncthreads();
    const int b = base;
    __syncthreads();
    if (b >= n) break;
    const int e = min(b + FILL_CHUNK, n);
    for (int i = b + (int)threadIdx.x; i < e; i += 256) {
      int d = dst[i];
      if (d >= lo && d < hi) {
        int p = atomicAdd(&cursor[d], 1);
        col[p] = src[i];
      }
    }
  }
}

// ---- neighbor gather v2: 4-way quarter split ----
// Wave = 4 quarters x 16 lanes; each quarter owns one edge per iteration with
// 16B/lane dwordx4 row loads -> 4 rows in flight per load instruction (vs 2
// rows / 8B in round 9). Combine across quarters with 2 shfl_xor at the end.
__global__ __launch_bounds__(256) void gather_kernel(const unsigned short* __restrict__ x,
    const int* __restrict__ rp, const int* __restrict__ col,
    unsigned short* __restrict__ agg, int n) {
  int wid = (blockIdx.x * 256 + threadIdx.x) >> 6;
  int lane = threadIdx.x & 63;
  if (wid >= n) return;
  const int q = lane >> 4;      // quarter 0..3
  const int l16 = lane & 15;    // 16 lanes x 16 B = 256 B row
  const ulonglong2* xv = (const ulonglong2*)x;

  float a[8];
#pragma unroll
  for (int k = 0; k < 8; ++k) a[k] = 0.f;
  if (q == 0) add8(a, xv[(size_t)wid * 16 + l16]);  // self row

  const int beg = rp[wid], end = rp[wid + 1];
  int j = beg;
  for (; j + 4 <= end; j += 4) {
    int c = col[j + q];
    add8(a, xv[(size_t)c * 16 + l16]);
  }
  if (j + q < end) {  // tail: quarters 0..rem-1 take one edge each
    int c = col[j + q];
    add8(a, xv[(size_t)c * 16 + l16]);
  }
#pragma unroll
  for (int k = 0; k < 8; ++k) {
    a[k] += __shfl_xor(a[k], 16, 64);
    a[k] += __shfl_xor(a[k], 32, 64);
  }
  if (q == 0) {
    ulonglong2 r;
    r.x = (u64)f2b(a[0]) | ((u64)f2b(a[1]) << 16) | ((u64)f2b(a[2]) << 32) | ((u64)f2b(a[3]) << 48);
    r.y = (u64)f2b(a[4]) | ((u64)f2b(a[5]) << 16) | ((u64)f2b(a[6]) << 32) | ((u64)f2b(a[7]) << 48);
    ((ulonglong2*)agg)[(size_t)wid * 16 + l16] = r;
  }
}

// ---- GEMM1: H = relu(A @ W1 + b1) ----
__global__ __launch_bounds__(256) void gemm1_kernel(
    const unsigned short* __restrict__ A, const unsigned short* __restrict__ W1T,
    const float* __restrict__ b1, unsigned short* __restrict__ H, int n) {
  const int wave = threadIdx.x >> 6;
  const int lane = threadIdx.x & 63;
  const int lr = lane & 15, lg = lane >> 4;
  const int rowBase = blockIdx.x * 64 + wave * 16;
  short8 a[4];
#pragma unroll
  for (int kt = 0; kt < 4; ++kt)
    a[kt] = *(const short8*)(A + (size_t)(rowBase + lr) * FEAT + kt * 32 + lg * 8);
  f32x4 acc[8];
#pragma unroll
  for (int ct = 0; ct < 8; ++ct) {
    const unsigned short* bp = W1T + (size_t)(ct * 16 + lr) * FEAT + lg * 8;
    f32x4 c = {0.f, 0.f, 0.f, 0.f};
    c = mfma16(a[0], *(const short8*)(bp), c);
    c = mfma16(a[1], *(const short8*)(bp + 32), c);
    c = mfma16(a[2], *(const short8*)(bp + 64), c);
    c = mfma16(a[3], *(const short8*)(bp + 96), c);
    acc[ct] = c;
  }
#pragma unroll
  for (int ct = 0; ct < 8; ++ct) {
    const int c = ct * 16 + lr;
    const float bias = b1[c];
#pragma unroll
    for (int j = 0; j < 4; ++j) {
      const int row = rowBase + lg * 4 + j;
      if (row < n) {
        float v = acc[ct][j] + bias;
        H[(size_t)row * FEAT + c] = f2b(v > 0.f ? v : 0.f);
      }
    }
  }
}

// ================= LDS-staged GEMM2 passes (round-11 structure) =================
// 128-col slices (32 KB stage) -> 4 blocks/CU; softmax in exp2 domain.

__global__ __launch_bounds__(512) void statT_kernel(
    const unsigned short* __restrict__ H, const unsigned short* __restrict__ W2T,
    const float* __restrict__ b2, float* __restrict__ pm, float* __restrict__ ps,
    int nPad) {
  __shared__ short8 ldsB[2048];   // 32 KB
  __shared__ float ldsBias[128];
  const int wave = threadIdx.x >> 6;
  const int lane = threadIdx.x & 63;
  const int lr = lane & 15, lg = lane >> 4;
  const int nRowBlk = nPad >> 8;
  const int rowBlk = blockIdx.x % nRowBlk;
  const int colBlk = blockIdx.x / nRowBlk;   // [0,16)
  const int rowBase = rowBlk * 256 + wave * 32;
  const int colBase = colBlk * 128;

#pragma unroll
  for (int r = 0; r < 4; ++r) {
    const int p = r * 8 + wave;
    const int ct = p >> 2, q = p & 3;
    ldsB[p * 64 + lane] =
        *(const short8*)(W2T + (size_t)(colBase + ct * 16 + lr) * FEAT + (q * 4 + lg) * 8);
  }
  if (threadIdx.x < 128) ldsBias[threadIdx.x] = b2[colBase + threadIdx.x] * LOG2E;

  short8 a[2][4];
#pragma unroll
  for (int g = 0; g < 2; ++g)
#pragma unroll
    for (int kt = 0; kt < 4; ++kt)
      a[g][kt] = *(const short8*)(H + (size_t)(rowBase + g * 16 + lr) * FEAT + kt * 32 + lg * 8);
  __syncthreads();

  float m[2][4], s[2][4];
#pragma unroll
  for (int g = 0; g < 2; ++g)
#pragma unroll
    for (int j = 0; j < 4; ++j) { m[g][j] = -1e30f; s[g][j] = 0.f; }

#pragma unroll 4
  for (int ct = 0; ct < 8; ++ct) {
    short8 q0 = ldsB[(ct * 4 + 0) * 64 + lane];
    short8 q1 = ldsB[(ct * 4 + 1) * 64 + lane];
    short8 q2 = ldsB[(ct * 4 + 2) * 64 + lane];
    short8 q3 = ldsB[(ct * 4 + 3) * 64 + lane];
    f32x4 c0 = {0.f, 0.f, 0.f, 0.f};
    f32x4 c1 = {0.f, 0.f, 0.f, 0.f};
    c0 = mfma16(a[0][0], q0, c0);
    c1 = mfma16(a[1][0], q0, c1);
    c0 = mfma16(a[0][1], q1, c0);
    c1 = mfma16(a[1][1], q1, c1);
    c0 = mfma16(a[0][2], q2, c0);
    c1 = mfma16(a[1][2], q2, c1);
    c0 = mfma16(a[0][3], q3, c0);
    c1 = mfma16(a[1][3], q3, c1);
    const float bs = ldsBias[ct * 16 + lr];
    float d0[4], d1[4];
#pragma unroll
    for (int j = 0; j < 4; ++j) {
      d0[j] = c0[j] + bs - m[0][j];
      d1[j] = c1[j] + bs - m[1][j];
    }
    float dmax = fmaxf(fmaxf(fmaxf(d0[0], d0[1]), fmaxf(d0[2], d0[3])),
                       fmaxf(fmaxf(d1[0], d1[1]), fmaxf(d1[2], d1[3])));
    if (__any(dmax > 12.f)) {
#pragma unroll
      for (int j = 0; j < 4; ++j) {
        float e0 = d0[j] + m[0][j], e1 = d1[j] + m[1][j];
        float nm0 = fmaxf(m[0][j], e0);
        s[0][j] = s[0][j] * exp2x(m[0][j] - nm0) + exp2x(e0 - nm0);
        m[0][j] = nm0;
        float nm1 = fmaxf(m[1][j], e1);
        s[1][j] = s[1][j] * exp2x(m[1][j] - nm1) + exp2x(e1 - nm1);
        m[1][j] = nm1;
      }
    } else {
#pragma unroll
      for (int j = 0; j < 4; ++j) {
        s[0][j] += exp2x(d0[j]);
        s[1][j] += exp2x(d1[j]);
      }
    }
  }
#pragma unroll
  for (int g = 0; g < 2; ++g)
#pragma unroll
    for (int j = 0; j < 4; ++j) {
#pragma unroll
      for (int d = 1; d < 16; d <<= 1) {
        float om = __shfl_xor(m[g][j], d, 64);
        float os = __shfl_xor(s[g][j], d, 64);
        float nm = fmaxf(m[g][j], om);
        s[g][j] = s[g][j] * exp2x(m[g][j] - nm) + os * exp2x(om - nm);
        m[g][j] = nm;
      }
    }
  if (lr == 0) {
#pragma unroll
    for (int g = 0; g < 2; ++g)
#pragma unroll
      for (int j = 0; j < 4; ++j) {
        const int row = rowBase + g * 16 + lg * 4 + j;
        pm[(size_t)colBlk * nPad + row] = m[g][j];
        ps[(size_t)colBlk * nPad + row] = s[g][j];
      }
  }
}

__global__ void mergeT_kernel(const float* __restrict__ pm, const float* __restrict__ ps,
                              float* __restrict__ T, int nPad) {
  int r = blockIdx.x * 256 + threadIdx.x;
  if (r < nPad) {
    float M = pm[r];
#pragma unroll
    for (int k = 1; k < 16; ++k) M = fmaxf(M, pm[(size_t)k * nPad + r]);
    float S = 0.f;
#pragma unroll
    for (int k = 0; k < 16; ++k) S += ps[(size_t)k * nPad + r] * exp2x(pm[(size_t)k * nPad + r] - M);
    T[r] = M + __log2f(S);
  }
}

__global__ __launch_bounds__(512) void fpacc_kernel(
    const unsigned short* __restrict__ H, const unsigned short* __restrict__ W2T,
    const float* __restrict__ b2, const float* __restrict__ T,
    float* __restrict__ partials, int n, int nPad) {
  __shared__ short8 ldsB[2048];   // 32 KB
  __shared__ float ldsBias[128];
  __shared__ float fp_w[8][128];  // 4 KB
  const int wave = threadIdx.x >> 6;
  const int lane = threadIdx.x & 63;
  const int lr = lane & 15, lg = lane >> 4;
  const int nRowBlk = nPad >> 8;
  const int rowBlk = blockIdx.x % nRowBlk;
  const int colBlk = blockIdx.x / nRowBlk;
  const int rowBase = rowBlk * 256 + wave * 32;
  const int colBase = colBlk * 128;

#pragma unroll
  for (int r = 0; r < 4; ++r) {
    const int p = r * 8 + wave;
    const int ct = p >> 2, q = p & 3;
    ldsB[p * 64 + lane] =
        *(const short8*)(W2T + (size_t)(colBase + ct * 16 + lr) * FEAT + (q * 4 + lg) * 8);
  }
  if (threadIdx.x < 128) ldsBias[threadIdx.x] = b2[colBase + threadIdx.x] * LOG2E;

  short8 a[2][4];
#pragma unroll
  for (int g = 0; g < 2; ++g)
#pragma unroll
    for (int kt = 0; kt < 4; ++kt)
      a[g][kt] = *(const short8*)(H + (size_t)(rowBase + g * 16 + lr) * FEAT + kt * 32 + lg * 8);
  float Tq[2][4];
#pragma unroll
  for (int g = 0; g < 2; ++g)
#pragma unroll
    for (int j = 0; j < 4; ++j) {
      const int row = rowBase + g * 16 + lg * 4 + j;
      Tq[g][j] = (row < n) ? T[row] : 1e30f;
    }
  __syncthreads();

#pragma unroll 4
  for (int ct = 0; ct < 8; ++ct) {
    short8 q0 = ldsB[(ct * 4 + 0) * 64 + lane];
    short8 q1 = ldsB[(ct * 4 + 1) * 64 + lane];
    short8 q2 = ldsB[(ct * 4 + 2) * 64 + lane];
    short8 q3 = ldsB[(ct * 4 + 3) * 64 + lane];
    f32x4 c0 = {0.f, 0.f, 0.f, 0.f};
    f32x4 c1 = {0.f, 0.f, 0.f, 0.f};
    c0 = mfma16(a[0][0], q0, c0);
    c1 = mfma16(a[1][0], q0, c1);
    c0 = mfma16(a[0][1], q1, c0);
    c1 = mfma16(a[1][1], q1, c1);
    c0 = mfma16(a[0][2], q2, c0);
    c1 = mfma16(a[1][2], q2, c1);
    c0 = mfma16(a[0][3], q3, c0);
    c1 = mfma16(a[1][3], q3, c1);
    const float bs = ldsBias[ct * 16 + lr];
    float p = exp2x(c0[0] + (bs - Tq[0][0])) + exp2x(c0[1] + (bs - Tq[0][1])) +
              exp2x(c0[2] + (bs - Tq[0][2])) + exp2x(c0[3] + (bs - Tq[0][3])) +
              exp2x(c1[0] + (bs - Tq[1][0])) + exp2x(c1[1] + (bs - Tq[1][1])) +
              exp2x(c1[2] + (bs - Tq[1][2])) + exp2x(c1[3] + (bs - Tq[1][3]));
    p += __shfl_xor(p, 16, 64);
    p += __shfl_xor(p, 32, 64);
    if (lg == 0) fp_w[wave][ct * 16 + lr] = p;
  }
  __syncthreads();
  if (threadIdx.x < 128) {
    float sum = 0.f;
#pragma unroll
    for (int w = 0; w < 8; ++w) sum += fp_w[w][threadIdx.x];
    partials[(size_t)rowBlk * FPL + colBase + threadIdx.x] += sum;
  }
}

__global__ void reduce_kernel(const float* __restrict__ partials, float* __restrict__ out, int nPart) {
  int c = blockIdx.x * 256 + threadIdx.x;
  if (c < FPL) {
    float s = 0.f;
    for (int p = 0; p < nPart; ++p) s += partials[(size_t)p * FPL + c];
    out[c] = s;
  }
}

extern "C" void kernel_launch(void* const* d_in, const int* in_sizes, int n_in,
                              void* d_out, int out_size, void* d_ws, size_t ws_size,
                              hipStream_t stream) {
  const float* atoms = (const float*)d_in[0];
  const float* W1 = (const float*)d_in[1];
  const float* b1 = (const float*)d_in[2];
  const float* W2 = (const float*)d_in[3];
  const float* b2 = (const float*)d_in[4];
  const int* esrc = (const int*)d_in[5];
  const int* edst = (const int*)d_in[6];
  const int nAtoms = in_sizes[0] / FEAT;
  const int nEdges = in_sizes[5];
  if (nAtoms <= 0) return;

  const int g2Blocks = (nAtoms + 255) / 256;
  const int nPad = g2Blocks * 256;
  const int g1Blocks = nPad / 64;
  const int nChunks = (nAtoms + 1023) / 1024;

  size_t off = 0;
  auto alloc = [&](size_t bytes) -> void* {
    void* p = (char*)d_ws + off;
    off += (bytes + 255) & ~(size_t)255;
    return p;
  };
  unsigned short* P = (unsigned short*)alloc((size_t)nPad * FEAT * 2);
  unsigned short* Q = (unsigned short*)alloc((size_t)nPad * FEAT * 2);
  unsigned short* W1T = (unsigned short*)alloc((size_t)FEAT * FEAT * 2);
  unsigned short* W2T = (unsigned short*)alloc((size_t)FEAT * FPL * 2);
  int* counts = (int*)alloc((size_t)nAtoms * 4);
  int* cursor = (int*)alloc((size_t)nAtoms * 4);
  int* rp = (int*)alloc(((size_t)nAtoms + 1) * 4);
  int* ex = (int*)alloc((size_t)nAtoms * 4);
  int* chunkSum = (int*)alloc((size_t)nChunks * 4);
  int* chunkOff = (int*)alloc((size_t)nChunks * 4);
  int* col = (int*)alloc((size_t)nEdges * 4);
  int* work = (int*)alloc(8 * 4);
  float* pm = (float*)alloc((size_t)16 * nPad * 4);
  float* ps = (float*)alloc((size_t)16 * nPad * 4);
  float* Trow = (float*)alloc((size_t)nPad * 4);
  float* partials = (float*)alloc((size_t)g2Blocks * FPL * 4);

  hipMemsetAsync(counts, 0, (size_t)nAtoms * 4, stream);
  hipMemsetAsync(work, 0, 8 * 4, stream);
  hipMemsetAsync(partials, 0, (size_t)g2Blocks * FPL * 4, stream);
  hipMemsetAsync(P + (size_t)nAtoms * FEAT, 0, (size_t)(nPad - nAtoms) * FEAT * 2, stream);
  hipMemsetAsync(Q + (size_t)nAtoms * FEAT, 0, (size_t)(nPad - nAtoms) * FEAT * 2, stream);

  const int n2 = in_sizes[0] / 2;
  cvt_kernel<<<(n2 + 255) / 256, 256, 0, stream>>>(atoms, P, n2);
  cvtT_kernel<<<(FEAT * FEAT + 255) / 256, 256, 0, stream>>>(W1, W1T, FEAT, FEAT, 1.0f);
  cvtT_kernel<<<(FEAT * FPL + 255) / 256, 256, 0, stream>>>(W2, W2T, FEAT, FPL, LOG2E);
  count_kernel<<<(nEdges + 255) / 256, 256, 0, stream>>>(edst, counts, nEdges);
  scan1_kernel<<<nChunks, 1024, 0, stream>>>(counts, ex, chunkSum, nAtoms);
  scan2_kernel<<<1, 1024, 0, stream>>>(chunkSum, chunkOff, nChunks);
  scan3_kernel<<<(nAtoms + 255) / 256, 256, 0, stream>>>(ex, chunkOff, chunkSum, rp, nAtoms, nChunks);
  copy_kernel<<<(nAtoms + 255) / 256, 256, 0, stream>>>(rp, cursor, nAtoms);
  fillx_kernel<<<1024, 256, 0, stream>>>(esrc, edst, cursor, col, work, nEdges, nAtoms);

  unsigned short* x = P;
  unsigned short* y = Q;
  for (int step = 0; step < 3; ++step) {
    gather_kernel<<<(nAtoms + 3) / 4, 256, 0, stream>>>(x, rp, col, y, nAtoms);
    gemm1_kernel<<<g1Blocks, 256, 0, stream>>>(y, W1T, b1, y, nAtoms);
    statT_kernel<<<g2Blocks * 16, 512, 0, stream>>>(y, W2T, b2, pm, ps, nPad);
    mergeT_kernel<<<(nPad + 255) / 256, 256, 0, stream>>>(pm, ps, Trow, nPad);
    fpacc_kernel<<<g2Blocks * 16, 512, 0, stream>>>(y, W2T, b2, Trow, partials, nAtoms, nPad);
    unsigned short* t = x; x = y; y = t;
  }
  reduce_kernel<<<(FPL + 255) / 256, 256, 0, stream>>>(partials, (float*)d_out, g2Blocks);
}

// Round 14
// 750.897 us; speedup vs baseline: 1.0616x; 1.0616x over previous
//
#include <hip/hip_runtime.h>

typedef short short8 __attribute__((ext_vector_type(8)));
typedef __bf16 bf16x8 __attribute__((ext_vector_type(8)));
typedef float f32x4 __attribute__((ext_vector_type(4)));
typedef unsigned long long u64;

#define FEAT 128
#define FPL 2048
#define LOG2E 1.4426950408889634f

__device__ __forceinline__ float b2f(unsigned int u) {
  union { unsigned int u; float f; } c; c.u = u << 16; return c.f;
}
__device__ __forceinline__ unsigned short f2b(float f) {
  union { float f; unsigned int u; } c; c.f = f;
  unsigned int r = c.u + 0x7fffu + ((c.u >> 16) & 1u);
  return (unsigned short)(r >> 16);
}
__device__ __forceinline__ f32x4 mfma16(short8 a, short8 b, f32x4 c) {
  return __builtin_amdgcn_mfma_f32_16x16x32_bf16(
      __builtin_bit_cast(bf16x8, a), __builtin_bit_cast(bf16x8, b), c, 0, 0, 0);
}
__device__ __forceinline__ float exp2x(float x) {
  float r; asm("v_exp_f32 %0, %1" : "=v"(r) : "v"(x)); return r;
}
__device__ __forceinline__ void add8(float* a, ulonglong2 v) {
  u64 lo = v.x, hi = v.y;
  a[0] += b2f((unsigned int)(lo & 0xffffu));
  a[1] += b2f((unsigned int)((lo >> 16) & 0xffffu));
  a[2] += b2f((unsigned int)((lo >> 32) & 0xffffu));
  a[3] += b2f((unsigned int)(lo >> 48));
  a[4] += b2f((unsigned int)(hi & 0xffffu));
  a[5] += b2f((unsigned int)((hi >> 16) & 0xffffu));
  a[6] += b2f((unsigned int)((hi >> 32) & 0xffffu));
  a[7] += b2f((unsigned int)(hi >> 48));
}

// ---- conversion kernels ----
__global__ void cvt_kernel(const float* __restrict__ in, unsigned short* __restrict__ out, int n2) {
  int i = blockIdx.x * 256 + threadIdx.x;
  if (i < n2) {
    float2 v = ((const float2*)in)[i];
    unsigned int lo = f2b(v.x), hi = f2b(v.y);
    ((unsigned int*)out)[i] = lo | (hi << 16);
  }
}

__global__ void cvtT_kernel(const float* __restrict__ W, unsigned short* __restrict__ WT,
                            int K, int N, float scale) {
  int i = blockIdx.x * 256 + threadIdx.x;
  if (i < K * N) {
    int k = i / N, c = i - k * N;
    WT[(size_t)c * K + k] = f2b(W[i] * scale);
  }
}

// ---- CSR build ----
__global__ void count_kernel(const int* __restrict__ dst, int* __restrict__ cnt, int n) {
  int i = blockIdx.x * 256 + threadIdx.x;
  if (i < n) atomicAdd(&cnt[dst[i]], 1);
}

__global__ __launch_bounds__(1024) void scan1_kernel(const int* __restrict__ cnt,
    int* __restrict__ ex, int* __restrict__ chunkSum, int n) {
  __shared__ int sd[1024];
  const int i = blockIdx.x * 1024 + threadIdx.x;
  int v = (i < n) ? cnt[i] : 0;
  sd[threadIdx.x] = v;
  __syncthreads();
  int sum = v;
  for (int off = 1; off < 1024; off <<= 1) {
    int t = (threadIdx.x >= (unsigned)off) ? sd[threadIdx.x - off] : 0;
    __syncthreads();
    sum += t;
    sd[threadIdx.x] = sum;
    __syncthreads();
  }
  if (i < n) ex[i] = sum - v;
  if (threadIdx.x == 1023) chunkSum[blockIdx.x] = sum;
}

__global__ __launch_bounds__(1024) void scan2_kernel(const int* __restrict__ chunkSum,
    int* __restrict__ chunkOff, int nChunks) {
  __shared__ int sd[1024];
  int v = (threadIdx.x < (unsigned)nChunks) ? chunkSum[threadIdx.x] : 0;
  sd[threadIdx.x] = v;
  __syncthreads();
  int sum = v;
  for (int off = 1; off < 1024; off <<= 1) {
    int t = (threadIdx.x >= (unsigned)off) ? sd[threadIdx.x - off] : 0;
    __syncthreads();
    sum += t;
    sd[threadIdx.x] = sum;
    __syncthreads();
  }
  if (threadIdx.x < (unsigned)nChunks) chunkOff[threadIdx.x] = sum - v;
}

__global__ void scan3_kernel(const int* __restrict__ ex, const int* __restrict__ chunkOff,
    const int* __restrict__ chunkSum, int* __restrict__ rp, int n, int nChunks) {
  int i = blockIdx.x * 256 + threadIdx.x;
  if (i < n) rp[i] = ex[i] + chunkOff[i >> 10];
  if (i == 0) rp[n] = chunkOff[nChunks - 1] + chunkSum[nChunks - 1];
}

__global__ void copy_kernel(const int* __restrict__ a, int* __restrict__ b, int n) {
  int i = blockIdx.x * 256 + threadIdx.x;
  if (i < n) b[i] = a[i];
}

// CSR fill (round-11 proven variant, 78 us measured best).
__global__ __launch_bounds__(256) void fillx_kernel(const int* __restrict__ src,
    const int* __restrict__ dst, int* __restrict__ cursor, int* __restrict__ col,
    int n, int nAtoms) {
  const int part = blockIdx.x & 7;
  const int blkInPart = blockIdx.x >> 3;
  const int nBlkPerPart = gridDim.x >> 3;
  const int partSize = (nAtoms + 7) >> 3;
  const int lo = part * partSize;
  const int hi = min(lo + partSize, nAtoms);
  const int stride = nBlkPerPart * 256;
  for (int i = blkInPart * 256 + (int)threadIdx.x; i < n; i += stride) {
    int d = __builtin_nontemporal_load(&dst[i]);
    if (d >= lo && d < hi) {
      int s = __builtin_nontemporal_load(&src[i]);
      int p = atomicAdd(&cursor[d], 1);
      col[p] = s;
    }
  }
}

// ---- neighbor gather: 4-way quarter split + 2-edge unroll ----
// Each 16-lane quarter owns 2 edges per iteration (2 independent col->row
// load chains in flight per lane) -- attacks the serial load-latency chain.
__global__ __launch_bounds__(256) void gather_kernel(const unsigned short* __restrict__ x,
    const int* __restrict__ rp, const int* __restrict__ col,
    unsigned short* __restrict__ agg, int n) {
  int wid = (blockIdx.x * 256 + threadIdx.x) >> 6;
  int lane = threadIdx.x & 63;
  if (wid >= n) return;
  const int q = lane >> 4;
  const int l16 = lane & 15;
  const ulonglong2* xv = (const ulonglong2*)x;

  float a[8];
#pragma unroll
  for (int k = 0; k < 8; ++k) a[k] = 0.f;
  if (q == 0) add8(a, xv[(size_t)wid * 16 + l16]);

  const int beg = rp[wid], end = rp[wid + 1];
  int j = beg;
  for (; j + 8 <= end; j += 8) {
    int c0 = col[j + q];
    int c1 = col[j + 4 + q];
    ulonglong2 v0 = xv[(size_t)c0 * 16 + l16];
    ulonglong2 v1 = xv[(size_t)c1 * 16 + l16];
    add8(a, v0);
    add8(a, v1);
  }
  if (j + 4 <= end) {
    int c = col[j + q];
    add8(a, xv[(size_t)c * 16 + l16]);
    j += 4;
  }
  if (j + q < end) {
    int c = col[j + q];
    add8(a, xv[(size_t)c * 16 + l16]);
  }
#pragma unroll
  for (int k = 0; k < 8; ++k) {
    a[k] += __shfl_xor(a[k], 16, 64);
    a[k] += __shfl_xor(a[k], 32, 64);
  }
  if (q == 0) {
    ulonglong2 r;
    r.x = (u64)f2b(a[0]) | ((u64)f2b(a[1]) << 16) | ((u64)f2b(a[2]) << 32) | ((u64)f2b(a[3]) << 48);
    r.y = (u64)f2b(a[4]) | ((u64)f2b(a[5]) << 16) | ((u64)f2b(a[6]) << 32) | ((u64)f2b(a[7]) << 48);
    ((ulonglong2*)agg)[(size_t)wid * 16 + l16] = r;
  }
}

// ---- GEMM1: H = relu(A @ W1 + b1) ----
__global__ __launch_bounds__(256) void gemm1_kernel(
    const unsigned short* __restrict__ A, const unsigned short* __restrict__ W1T,
    const float* __restrict__ b1, unsigned short* __restrict__ H, int n) {
  const int wave = threadIdx.x >> 6;
  const int lane = threadIdx.x & 63;
  const int lr = lane & 15, lg = lane >> 4;
  const int rowBase = blockIdx.x * 64 + wave * 16;
  short8 a[4];
#pragma unroll
  for (int kt = 0; kt < 4; ++kt)
    a[kt] = *(const short8*)(A + (size_t)(rowBase + lr) * FEAT + kt * 32 + lg * 8);
  f32x4 acc[8];
#pragma unroll
  for (int ct = 0; ct < 8; ++ct) {
    const unsigned short* bp = W1T + (size_t)(ct * 16 + lr) * FEAT + lg * 8;
    f32x4 c = {0.f, 0.f, 0.f, 0.f};
    c = mfma16(a[0], *(const short8*)(bp), c);
    c = mfma16(a[1], *(const short8*)(bp + 32), c);
    c = mfma16(a[2], *(const short8*)(bp + 64), c);
    c = mfma16(a[3], *(const short8*)(bp + 96), c);
    acc[ct] = c;
  }
#pragma unroll
  for (int ct = 0; ct < 8; ++ct) {
    const int c = ct * 16 + lr;
    const float bias = b1[c];
#pragma unroll
    for (int j = 0; j < 4; ++j) {
      const int row = rowBase + lg * 4 + j;
      if (row < n) {
        float v = acc[ct][j] + bias;
        H[(size_t)row * FEAT + c] = f2b(v > 0.f ? v : 0.f);
      }
    }
  }
}

// ================= LDS-staged GEMM2 passes (round-11 proven) =================
// 128-col slices (32 KB stage), exp2 domain, DEFER-MAX online softmax.
// Round-13 lesson: logits grow unboundedly across steps (features amplify
// ~32x per aggregation); fixed-shift overflows. Per-row max is REQUIRED.

__global__ __launch_bounds__(512) void statT_kernel(
    const unsigned short* __restrict__ H, const unsigned short* __restrict__ W2T,
    const float* __restrict__ b2, float* __restrict__ pm, float* __restrict__ ps,
    int nPad) {
  __shared__ short8 ldsB[2048];   // 32 KB
  __shared__ float ldsBias[128];
  const int wave = threadIdx.x >> 6;
  const int lane = threadIdx.x & 63;
  const int lr = lane & 15, lg = lane >> 4;
  const int nRowBlk = nPad >> 8;
  const int rowBlk = blockIdx.x % nRowBlk;
  const int colBlk = blockIdx.x / nRowBlk;   // [0,16)
  const int rowBase = rowBlk * 256 + wave * 32;
  const int colBase = colBlk * 128;

#pragma unroll
  for (int r = 0; r < 4; ++r) {
    const int p = r * 8 + wave;
    const int ct = p >> 2, q = p & 3;
    ldsB[p * 64 + lane] =
        *(const short8*)(W2T + (size_t)(colBase + ct * 16 + lr) * FEAT + (q * 4 + lg) * 8);
  }
  if (threadIdx.x < 128) ldsBias[threadIdx.x] = b2[colBase + threadIdx.x] * LOG2E;

  short8 a[2][4];
#pragma unroll
  for (int g = 0; g < 2; ++g)
#pragma unroll
    for (int kt = 0; kt < 4; ++kt)
      a[g][kt] = *(const short8*)(H + (size_t)(rowBase + g * 16 + lr) * FEAT + kt * 32 + lg * 8);
  __syncthreads();

  float m[2][4], s[2][4];
#pragma unroll
  for (int g = 0; g < 2; ++g)
#pragma unroll
    for (int j = 0; j < 4; ++j) { m[g][j] = -1e30f; s[g][j] = 0.f; }

#pragma unroll 4
  for (int ct = 0; ct < 8; ++ct) {
    short8 q0 = ldsB[(ct * 4 + 0) * 64 + lane];
    short8 q1 = ldsB[(ct * 4 + 1) * 64 + lane];
    short8 q2 = ldsB[(ct * 4 + 2) * 64 + lane];
    short8 q3 = ldsB[(ct * 4 + 3) * 64 + lane];
    f32x4 c0 = {0.f, 0.f, 0.f, 0.f};
    f32x4 c1 = {0.f, 0.f, 0.f, 0.f};
    c0 = mfma16(a[0][0], q0, c0);
    c1 = mfma16(a[1][0], q0, c1);
    c0 = mfma16(a[0][1], q1, c0);
    c1 = mfma16(a[1][1], q1, c1);
    c0 = mfma16(a[0][2], q2, c0);
    c1 = mfma16(a[1][2], q2, c1);
    c0 = mfma16(a[0][3], q3, c0);
    c1 = mfma16(a[1][3], q3, c1);
    const float bs = ldsBias[ct * 16 + lr];
    float d0[4], d1[4];
#pragma unroll
    for (int j = 0; j < 4; ++j) {
      d0[j] = c0[j] + bs - m[0][j];
      d1[j] = c1[j] + bs - m[1][j];
    }
    float dmax = fmaxf(fmaxf(fmaxf(d0[0], d0[1]), fmaxf(d0[2], d0[3])),
                       fmaxf(fmaxf(d1[0], d1[1]), fmaxf(d1[2], d1[3])));
    if (__any(dmax > 12.f)) {
#pragma unroll
      for (int j = 0; j < 4; ++j) {
        float e0 = d0[j] + m[0][j], e1 = d1[j] + m[1][j];
        float nm0 = fmaxf(m[0][j], e0);
        s[0][j] = s[0][j] * exp2x(m[0][j] - nm0) + exp2x(e0 - nm0);
        m[0][j] = nm0;
        float nm1 = fmaxf(m[1][j], e1);
        s[1][j] = s[1][j] * exp2x(m[1][j] - nm1) + exp2x(e1 - nm1);
        m[1][j] = nm1;
      }
    } else {
#pragma unroll
      for (int j = 0; j < 4; ++j) {
        s[0][j] += exp2x(d0[j]);
        s[1][j] += exp2x(d1[j]);
      }
    }
  }
#pragma unroll
  for (int g = 0; g < 2; ++g)
#pragma unroll
    for (int j = 0; j < 4; ++j) {
#pragma unroll
      for (int d = 1; d < 16; d <<= 1) {
        float om = __shfl_xor(m[g][j], d, 64);
        float os = __shfl_xor(s[g][j], d, 64);
        float nm = fmaxf(m[g][j], om);
        s[g][j] = s[g][j] * exp2x(m[g][j] - nm) + os * exp2x(om - nm);
        m[g][j] = nm;
      }
    }
  if (lr == 0) {
#pragma unroll
    for (int g = 0; g < 2; ++g)
#pragma unroll
      for (int j = 0; j < 4; ++j) {
        const int row = rowBase + g * 16 + lg * 4 + j;
        pm[(size_t)colBlk * nPad + row] = m[g][j];
        ps[(size_t)colBlk * nPad + row] = s[g][j];
      }
  }
}

__global__ void mergeT_kernel(const float* __restrict__ pm, const float* __restrict__ ps,
                              float* __restrict__ T, int nPad) {
  int r = blockIdx.x * 256 + threadIdx.x;
  if (r < nPad) {
    float M = pm[r];
#pragma unroll
    for (int k = 1; k < 16; ++k) M = fmaxf(M, pm[(size_t)k * nPad + r]);
    float S = 0.f;
#pragma unroll
    for (int k = 0; k < 16; ++k) S += ps[(size_t)k * nPad + r] * exp2x(pm[(size_t)k * nPad + r] - M);
    T[r] = M + __log2f(S);
  }
}

__global__ __launch_bounds__(512) void fpacc_kernel(
    const unsigned short* __restrict__ H, const unsigned short* __restrict__ W2T,
    const float* __restrict__ b2, const float* __restrict__ T,
    float* __restrict__ partials, int n, int nPad) {
  __shared__ short8 ldsB[2048];   // 32 KB
  __shared__ float ldsBias[128];
  __shared__ float fp_w[8][128];  // 4 KB
  const int wave = threadIdx.x >> 6;
  const int lane = threadIdx.x & 63;
  const int lr = lane & 15, lg = lane >> 4;
  const int nRowBlk = nPad >> 8;
  const int rowBlk = blockIdx.x % nRowBlk;
  const int colBlk = blockIdx.x / nRowBlk;
  const int rowBase = rowBlk * 256 + wave * 32;
  const int colBase = colBlk * 128;

#pragma unroll
  for (int r = 0; r < 4; ++r) {
    const int p = r * 8 + wave;
    const int ct = p >> 2, q = p & 3;
    ldsB[p * 64 + lane] =
        *(const short8*)(W2T + (size_t)(colBase + ct * 16 + lr) * FEAT + (q * 4 + lg) * 8);
  }
  if (threadIdx.x < 128) ldsBias[threadIdx.x] = b2[colBase + threadIdx.x] * LOG2E;

  short8 a[2][4];
#pragma unroll
  for (int g = 0; g < 2; ++g)
#pragma unroll
    for (int kt = 0; kt < 4; ++kt)
      a[g][kt] = *(const short8*)(H + (size_t)(rowBase + g * 16 + lr) * FEAT + kt * 32 + lg * 8);
  float Tq[2][4];
#pragma unroll
  for (int g = 0; g < 2; ++g)
#pragma unroll
    for (int j = 0; j < 4; ++j) {
      const int row = rowBase + g * 16 + lg * 4 + j;
      Tq[g][j] = (row < n) ? T[row] : 1e30f;
    }
  __syncthreads();

#pragma unroll 4
  for (int ct = 0; ct < 8; ++ct) {
    short8 q0 = ldsB[(ct * 4 + 0) * 64 + lane];
    short8 q1 = ldsB[(ct * 4 + 1) * 64 + lane];
    short8 q2 = ldsB[(ct * 4 + 2) * 64 + lane];
    short8 q3 = ldsB[(ct * 4 + 3) * 64 + lane];
    f32x4 c0 = {0.f, 0.f, 0.f, 0.f};
    f32x4 c1 = {0.f, 0.f, 0.f, 0.f};
    c0 = mfma16(a[0][0], q0, c0);
    c1 = mfma16(a[1][0], q0, c1);
    c0 = mfma16(a[0][1], q1, c0);
    c1 = mfma16(a[1][1], q1, c1);
    c0 = mfma16(a[0][2], q2, c0);
    c1 = mfma16(a[1][2], q2, c1);
    c0 = mfma16(a[0][3], q3, c0);
    c1 = mfma16(a[1][3], q3, c1);
    const float bs = ldsBias[ct * 16 + lr];
    float p = exp2x(c0[0] + (bs - Tq[0][0])) + exp2x(c0[1] + (bs - Tq[0][1])) +
              exp2x(c0[2] + (bs - Tq[0][2])) + exp2x(c0[3] + (bs - Tq[0][3])) +
              exp2x(c1[0] + (bs - Tq[1][0])) + exp2x(c1[1] + (bs - Tq[1][1])) +
              exp2x(c1[2] + (bs - Tq[1][2])) + exp2x(c1[3] + (bs - Tq[1][3]));
    p += __shfl_xor(p, 16, 64);
    p += __shfl_xor(p, 32, 64);
    if (lg == 0) fp_w[wave][ct * 16 + lr] = p;
  }
  __syncthreads();
  if (threadIdx.x < 128) {
    float sum = 0.f;
#pragma unroll
    for (int w = 0; w < 8; ++w) sum += fp_w[w][threadIdx.x];
    partials[(size_t)rowBlk * FPL + colBase + threadIdx.x] += sum;
  }
}

__global__ void reduce_kernel(const float* __restrict__ partials, float* __restrict__ out, int nPart) {
  int c = blockIdx.x * 256 + threadIdx.x;
  if (c < FPL) {
    float s = 0.f;
    for (int p = 0; p < nPart; ++p) s += partials[(size_t)p * FPL + c];
    out[c] = s;
  }
}

extern "C" void kernel_launch(void* const* d_in, const int* in_sizes, int n_in,
                              void* d_out, int out_size, void* d_ws, size_t ws_size,
                              hipStream_t stream) {
  const float* atoms = (const float*)d_in[0];
  const float* W1 = (const float*)d_in[1];
  const float* b1 = (const float*)d_in[2];
  const float* W2 = (const float*)d_in[3];
  const float* b2 = (const float*)d_in[4];
  const int* esrc = (const int*)d_in[5];
  const int* edst = (const int*)d_in[6];
  const int nAtoms = in_sizes[0] / FEAT;
  const int nEdges = in_sizes[5];
  if (nAtoms <= 0) return;

  const int g2Blocks = (nAtoms + 255) / 256;
  const int nPad = g2Blocks * 256;
  const int g1Blocks = nPad / 64;
  const int nChunks = (nAtoms + 1023) / 1024;

  size_t off = 0;
  auto alloc = [&](size_t bytes) -> void* {
    void* p = (char*)d_ws + off;
    off += (bytes + 255) & ~(size_t)255;
    return p;
  };
  unsigned short* P = (unsigned short*)alloc((size_t)nPad * FEAT * 2);
  unsigned short* Q = (unsigned short*)alloc((size_t)nPad * FEAT * 2);
  unsigned short* W1T = (unsigned short*)alloc((size_t)FEAT * FEAT * 2);
  unsigned short* W2T = (unsigned short*)alloc((size_t)FEAT * FPL * 2);
  int* counts = (int*)alloc((size_t)nAtoms * 4);
  int* cursor = (int*)alloc((size_t)nAtoms * 4);
  int* rp = (int*)alloc(((size_t)nAtoms + 1) * 4);
  int* ex = (int*)alloc((size_t)nAtoms * 4);
  int* chunkSum = (int*)alloc((size_t)nChunks * 4);
  int* chunkOff = (int*)alloc((size_t)nChunks * 4);
  int* col = (int*)alloc((size_t)nEdges * 4);
  float* pm = (float*)alloc((size_t)16 * nPad * 4);
  float* ps = (float*)alloc((size_t)16 * nPad * 4);
  float* Trow = (float*)alloc((size_t)nPad * 4);
  float* partials = (float*)alloc((size_t)g2Blocks * FPL * 4);

  hipMemsetAsync(counts, 0, (size_t)nAtoms * 4, stream);
  hipMemsetAsync(partials, 0, (size_t)g2Blocks * FPL * 4, stream);
  hipMemsetAsync(P + (size_t)nAtoms * FEAT, 0, (size_t)(nPad - nAtoms) * FEAT * 2, stream);
  hipMemsetAsync(Q + (size_t)nAtoms * FEAT, 0, (size_t)(nPad - nAtoms) * FEAT * 2, stream);

  const int n2 = in_sizes[0] / 2;
  cvt_kernel<<<(n2 + 255) / 256, 256, 0, stream>>>(atoms, P, n2);
  cvtT_kernel<<<(FEAT * FEAT + 255) / 256, 256, 0, stream>>>(W1, W1T, FEAT, FEAT, 1.0f);
  cvtT_kernel<<<(FEAT * FPL + 255) / 256, 256, 0, stream>>>(W2, W2T, FEAT, FPL, LOG2E);
  count_kernel<<<(nEdges + 255) / 256, 256, 0, stream>>>(edst, counts, nEdges);
  scan1_kernel<<<nChunks, 1024, 0, stream>>>(counts, ex, chunkSum, nAtoms);
  scan2_kernel<<<1, 1024, 0, stream>>>(chunkSum, chunkOff, nChunks);
  scan3_kernel<<<(nAtoms + 255) / 256, 256, 0, stream>>>(ex, chunkOff, chunkSum, rp, nAtoms, nChunks);
  copy_kernel<<<(nAtoms + 255) / 256, 256, 0, stream>>>(rp, cursor, nAtoms);
  fillx_kernel<<<1024, 256, 0, stream>>>(esrc, edst, cursor, col, nEdges, nAtoms);

  unsigned short* x = P;
  unsigned short* y = Q;
  for (int step = 0; step < 3; ++step) {
    gather_kernel<<<(nAtoms + 3) / 4, 256, 0, stream>>>(x, rp, col, y, nAtoms);
    gemm1_kernel<<<g1Blocks, 256, 0, stream>>>(y, W1T, b1, y, nAtoms);
    statT_kernel<<<g2Blocks * 16, 512, 0, stream>>>(y, W2T, b2, pm, ps, nPad);
    mergeT_kernel<<<(nPad + 255) / 256, 256, 0, stream>>>(pm, ps, Trow, nPad);
    fpacc_kernel<<<g2Blocks * 16, 512, 0, stream>>>(y, W2T, b2, Trow, partials, nAtoms, nPad);
    unsigned short* t = x; x = y; y = t;
  }
  reduce_kernel<<<(FPL + 255) / 256, 256, 0, stream>>>(partials, (float*)d_out, g2Blocks);
}

// Round 15
// 707.633 us; speedup vs baseline: 1.1265x; 1.0611x over previous
//
#include <hip/hip_runtime.h>

typedef short short8 __attribute__((ext_vector_type(8)));
typedef __bf16 bf16x8 __attribute__((ext_vector_type(8)));
typedef float f32x4 __attribute__((ext_vector_type(4)));
typedef unsigned long long u64;

#define FEAT 128
#define FPL 2048
#define LOG2E 1.4426950408889634f

__device__ __forceinline__ float b2f(unsigned int u) {
  union { unsigned int u; float f; } c; c.u = u << 16; return c.f;
}
__device__ __forceinline__ unsigned short f2b(float f) {
  union { float f; unsigned int u; } c; c.f = f;
  unsigned int r = c.u + 0x7fffu + ((c.u >> 16) & 1u);
  return (unsigned short)(r >> 16);
}
__device__ __forceinline__ f32x4 mfma16(short8 a, short8 b, f32x4 c) {
  return __builtin_amdgcn_mfma_f32_16x16x32_bf16(
      __builtin_bit_cast(bf16x8, a), __builtin_bit_cast(bf16x8, b), c, 0, 0, 0);
}
__device__ __forceinline__ float exp2x(float x) {
  float r; asm("v_exp_f32 %0, %1" : "=v"(r) : "v"(x)); return r;
}
__device__ __forceinline__ void add8(float* a, ulonglong2 v) {
  u64 lo = v.x, hi = v.y;
  a[0] += b2f((unsigned int)(lo & 0xffffu));
  a[1] += b2f((unsigned int)((lo >> 16) & 0xffffu));
  a[2] += b2f((unsigned int)((lo >> 32) & 0xffffu));
  a[3] += b2f((unsigned int)(lo >> 48));
  a[4] += b2f((unsigned int)(hi & 0xffffu));
  a[5] += b2f((unsigned int)((hi >> 16) & 0xffffu));
  a[6] += b2f((unsigned int)((hi >> 32) & 0xffffu));
  a[7] += b2f((unsigned int)(hi >> 48));
}

// ---- conversion kernels ----
__global__ void cvt_kernel(const float* __restrict__ in, unsigned short* __restrict__ out, int n2) {
  int i = blockIdx.x * 256 + threadIdx.x;
  if (i < n2) {
    float2 v = ((const float2*)in)[i];
    unsigned int lo = f2b(v.x), hi = f2b(v.y);
    ((unsigned int*)out)[i] = lo | (hi << 16);
  }
}

__global__ void cvtT_kernel(const float* __restrict__ W, unsigned short* __restrict__ WT,
                            int K, int N, float scale) {
  int i = blockIdx.x * 256 + threadIdx.x;
  if (i < K * N) {
    int k = i / N, c = i - k * N;
    WT[(size_t)c * K + k] = f2b(W[i] * scale);
  }
}

// ---- CSR build ----
// countrank: one returning-atomic pass yields BOTH the histogram (cnt) and
// each edge's rank within its dst row. Round-14 analysis: fillx's 61 MB WRITE
// was the returning-atomic memory-side RMW traffic, and the pipeline paid the
// 1.6M-atomic toll twice (count + fill). Now it's paid once; the fill becomes
// a pure-store pass.
__global__ void countrank_kernel(const int* __restrict__ dst, int* __restrict__ cnt,
                                 int* __restrict__ rank, int n) {
  int i = blockIdx.x * 256 + threadIdx.x;
  if (i < n) rank[i] = atomicAdd(&cnt[dst[i]], 1);
}

__global__ __launch_bounds__(1024) void scan1_kernel(const int* __restrict__ cnt,
    int* __restrict__ ex, int* __restrict__ chunkSum, int n) {
  __shared__ int sd[1024];
  const int i = blockIdx.x * 1024 + threadIdx.x;
  int v = (i < n) ? cnt[i] : 0;
  sd[threadIdx.x] = v;
  __syncthreads();
  int sum = v;
  for (int off = 1; off < 1024; off <<= 1) {
    int t = (threadIdx.x >= (unsigned)off) ? sd[threadIdx.x - off] : 0;
    __syncthreads();
    sum += t;
    sd[threadIdx.x] = sum;
    __syncthreads();
  }
  if (i < n) ex[i] = sum - v;
  if (threadIdx.x == 1023) chunkSum[blockIdx.x] = sum;
}

__global__ __launch_bounds__(1024) void scan2_kernel(const int* __restrict__ chunkSum,
    int* __restrict__ chunkOff, int nChunks) {
  __shared__ int sd[1024];
  int v = (threadIdx.x < (unsigned)nChunks) ? chunkSum[threadIdx.x] : 0;
  sd[threadIdx.x] = v;
  __syncthreads();
  int sum = v;
  for (int off = 1; off < 1024; off <<= 1) {
    int t = (threadIdx.x >= (unsigned)off) ? sd[threadIdx.x - off] : 0;
    __syncthreads();
    sum += t;
    sd[threadIdx.x] = sum;
    __syncthreads();
  }
  if (threadIdx.x < (unsigned)nChunks) chunkOff[threadIdx.x] = sum - v;
}

__global__ void scan3_kernel(const int* __restrict__ ex, const int* __restrict__ chunkOff,
    const int* __restrict__ chunkSum, int* __restrict__ rp, int n, int nChunks) {
  int i = blockIdx.x * 256 + threadIdx.x;
  if (i < n) rp[i] = ex[i] + chunkOff[i >> 10];
  if (i == 0) rp[n] = chunkOff[nChunks - 1] + chunkSum[nChunks - 1];
}

// Pure-store CSR fill: col[rp[d] + rank[i]] = src[i]. No atomics. 4-way
// dst-partitioned so each partition's col writes cluster in a ~1.6 MB
// L2-resident region; dst re-streamed 4x via nontemporal loads.
__global__ __launch_bounds__(256) void fillp_kernel(const int* __restrict__ src,
    const int* __restrict__ dst, const int* __restrict__ rank,
    const int* __restrict__ rp, int* __restrict__ col, int n, int nAtoms) {
  const int part = blockIdx.x & 3;
  const int blkInPart = blockIdx.x >> 2;
  const int nBlkPerPart = gridDim.x >> 2;
  const int partSize = (nAtoms + 3) >> 2;
  const int lo = part * partSize;
  const int hi = min(lo + partSize, nAtoms);
  const int stride = nBlkPerPart * 256;
  for (int i = blkInPart * 256 + (int)threadIdx.x; i < n; i += stride) {
    int d = __builtin_nontemporal_load(&dst[i]);
    if (d >= lo && d < hi) {
      col[rp[d] + rank[i]] = src[i];
    }
  }
}

// ---- neighbor gather: 4-way quarter split + 2-edge unroll (round-14) ----
__global__ __launch_bounds__(256) void gather_kernel(const unsigned short* __restrict__ x,
    const int* __restrict__ rp, const int* __restrict__ col,
    unsigned short* __restrict__ agg, int n) {
  int wid = (blockIdx.x * 256 + threadIdx.x) >> 6;
  int lane = threadIdx.x & 63;
  if (wid >= n) return;
  const int q = lane >> 4;
  const int l16 = lane & 15;
  const ulonglong2* xv = (const ulonglong2*)x;

  float a[8];
#pragma unroll
  for (int k = 0; k < 8; ++k) a[k] = 0.f;
  if (q == 0) add8(a, xv[(size_t)wid * 16 + l16]);

  const int beg = rp[wid], end = rp[wid + 1];
  int j = beg;
  for (; j + 8 <= end; j += 8) {
    int c0 = col[j + q];
    int c1 = col[j + 4 + q];
    ulonglong2 v0 = xv[(size_t)c0 * 16 + l16];
    ulonglong2 v1 = xv[(size_t)c1 * 16 + l16];
    add8(a, v0);
    add8(a, v1);
  }
  if (j + 4 <= end) {
    int c = col[j + q];
    add8(a, xv[(size_t)c * 16 + l16]);
    j += 4;
  }
  if (j + q < end) {
    int c = col[j + q];
    add8(a, xv[(size_t)c * 16 + l16]);
  }
#pragma unroll
  for (int k = 0; k < 8; ++k) {
    a[k] += __shfl_xor(a[k], 16, 64);
    a[k] += __shfl_xor(a[k], 32, 64);
  }
  if (q == 0) {
    ulonglong2 r;
    r.x = (u64)f2b(a[0]) | ((u64)f2b(a[1]) << 16) | ((u64)f2b(a[2]) << 32) | ((u64)f2b(a[3]) << 48);
    r.y = (u64)f2b(a[4]) | ((u64)f2b(a[5]) << 16) | ((u64)f2b(a[6]) << 32) | ((u64)f2b(a[7]) << 48);
    ((ulonglong2*)agg)[(size_t)wid * 16 + l16] = r;
  }
}

// ---- GEMM1: H = relu(A @ W1 + b1) ----
__global__ __launch_bounds__(256) void gemm1_kernel(
    const unsigned short* __restrict__ A, const unsigned short* __restrict__ W1T,
    const float* __restrict__ b1, unsigned short* __restrict__ H, int n) {
  const int wave = threadIdx.x >> 6;
  const int lane = threadIdx.x & 63;
  const int lr = lane & 15, lg = lane >> 4;
  const int rowBase = blockIdx.x * 64 + wave * 16;
  short8 a[4];
#pragma unroll
  for (int kt = 0; kt < 4; ++kt)
    a[kt] = *(const short8*)(A + (size_t)(rowBase + lr) * FEAT + kt * 32 + lg * 8);
  f32x4 acc[8];
#pragma unroll
  for (int ct = 0; ct < 8; ++ct) {
    const unsigned short* bp = W1T + (size_t)(ct * 16 + lr) * FEAT + lg * 8;
    f32x4 c = {0.f, 0.f, 0.f, 0.f};
    c = mfma16(a[0], *(const short8*)(bp), c);
    c = mfma16(a[1], *(const short8*)(bp + 32), c);
    c = mfma16(a[2], *(const short8*)(bp + 64), c);
    c = mfma16(a[3], *(const short8*)(bp + 96), c);
    acc[ct] = c;
  }
#pragma unroll
  for (int ct = 0; ct < 8; ++ct) {
    const int c = ct * 16 + lr;
    const float bias = b1[c];
#pragma unroll
    for (int j = 0; j < 4; ++j) {
      const int row = rowBase + lg * 4 + j;
      if (row < n) {
        float v = acc[ct][j] + bias;
        H[(size_t)row * FEAT + c] = f2b(v > 0.f ? v : 0.f);
      }
    }
  }
}

// ================= LDS-staged GEMM2 passes (round-11 proven, defer-max) =================

__global__ __launch_bounds__(512) void statT_kernel(
    const unsigned short* __restrict__ H, const unsigned short* __restrict__ W2T,
    const float* __restrict__ b2, float* __restrict__ pm, float* __restrict__ ps,
    int nPad) {
  __shared__ short8 ldsB[2048];   // 32 KB
  __shared__ float ldsBias[128];
  const int wave = threadIdx.x >> 6;
  const int lane = threadIdx.x & 63;
  const int lr = lane & 15, lg = lane >> 4;
  const int nRowBlk = nPad >> 8;
  const int rowBlk = blockIdx.x % nRowBlk;
  const int colBlk = blockIdx.x / nRowBlk;   // [0,16)
  const int rowBase = rowBlk * 256 + wave * 32;
  const int colBase = colBlk * 128;

#pragma unroll
  for (int r = 0; r < 4; ++r) {
    const int p = r * 8 + wave;
    const int ct = p >> 2, q = p & 3;
    ldsB[p * 64 + lane] =
        *(const short8*)(W2T + (size_t)(colBase + ct * 16 + lr) * FEAT + (q * 4 + lg) * 8);
  }
  if (threadIdx.x < 128) ldsBias[threadIdx.x] = b2[colBase + threadIdx.x] * LOG2E;

  short8 a[2][4];
#pragma unroll
  for (int g = 0; g < 2; ++g)
#pragma unroll
    for (int kt = 0; kt < 4; ++kt)
      a[g][kt] = *(const short8*)(H + (size_t)(rowBase + g * 16 + lr) * FEAT + kt * 32 + lg * 8);
  __syncthreads();

  float m[2][4], s[2][4];
#pragma unroll
  for (int g = 0; g < 2; ++g)
#pragma unroll
    for (int j = 0; j < 4; ++j) { m[g][j] = -1e30f; s[g][j] = 0.f; }

#pragma unroll 4
  for (int ct = 0; ct < 8; ++ct) {
    short8 q0 = ldsB[(ct * 4 + 0) * 64 + lane];
    short8 q1 = ldsB[(ct * 4 + 1) * 64 + lane];
    short8 q2 = ldsB[(ct * 4 + 2) * 64 + lane];
    short8 q3 = ldsB[(ct * 4 + 3) * 64 + lane];
    f32x4 c0 = {0.f, 0.f, 0.f, 0.f};
    f32x4 c1 = {0.f, 0.f, 0.f, 0.f};
    c0 = mfma16(a[0][0], q0, c0);
    c1 = mfma16(a[1][0], q0, c1);
    c0 = mfma16(a[0][1], q1, c0);
    c1 = mfma16(a[1][1], q1, c1);
    c0 = mfma16(a[0][2], q2, c0);
    c1 = mfma16(a[1][2], q2, c1);
    c0 = mfma16(a[0][3], q3, c0);
    c1 = mfma16(a[1][3], q3, c1);
    const float bs = ldsBias[ct * 16 + lr];
    float d0[4], d1[4];
#pragma unroll
    for (int j = 0; j < 4; ++j) {
      d0[j] = c0[j] + bs - m[0][j];
      d1[j] = c1[j] + bs - m[1][j];
    }
    float dmax = fmaxf(fmaxf(fmaxf(d0[0], d0[1]), fmaxf(d0[2], d0[3])),
                       fmaxf(fmaxf(d1[0], d1[1]), fmaxf(d1[2], d1[3])));
    if (__any(dmax > 12.f)) {
#pragma unroll
      for (int j = 0; j < 4; ++j) {
        float e0 = d0[j] + m[0][j], e1 = d1[j] + m[1][j];
        float nm0 = fmaxf(m[0][j], e0);
        s[0][j] = s[0][j] * exp2x(m[0][j] - nm0) + exp2x(e0 - nm0);
        m[0][j] = nm0;
        float nm1 = fmaxf(m[1][j], e1);
        s[1][j] = s[1][j] * exp2x(m[1][j] - nm1) + exp2x(e1 - nm1);
        m[1][j] = nm1;
      }
    } else {
#pragma unroll
      for (int j = 0; j < 4; ++j) {
        s[0][j] += exp2x(d0[j]);
        s[1][j] += exp2x(d1[j]);
      }
    }
  }
#pragma unroll
  for (int g = 0; g < 2; ++g)
#pragma unroll
    for (int j = 0; j < 4; ++j) {
#pragma unroll
      for (int d = 1; d < 16; d <<= 1) {
        float om = __shfl_xor(m[g][j], d, 64);
        float os = __shfl_xor(s[g][j], d, 64);
        float nm = fmaxf(m[g][j], om);
        s[g][j] = s[g][j] * exp2x(m[g][j] - nm) + os * exp2x(om - nm);
        m[g][j] = nm;
      }
    }
  if (lr == 0) {
#pragma unroll
    for (int g = 0; g < 2; ++g)
#pragma unroll
      for (int j = 0; j < 4; ++j) {
        const int row = rowBase + g * 16 + lg * 4 + j;
        pm[(size_t)colBlk * nPad + row] = m[g][j];
        ps[(size_t)colBlk * nPad + row] = s[g][j];
      }
  }
}

__global__ void mergeT_kernel(const float* __restrict__ pm, const float* __restrict__ ps,
                              float* __restrict__ T, int nPad) {
  int r = blockIdx.x * 256 + threadIdx.x;
  if (r < nPad) {
    float M = pm[r];
#pragma unroll
    for (int k = 1; k < 16; ++k) M = fmaxf(M, pm[(size_t)k * nPad + r]);
    float S = 0.f;
#pragma unroll
    for (int k = 0; k < 16; ++k) S += ps[(size_t)k * nPad + r] * exp2x(pm[(size_t)k * nPad + r] - M);
    T[r] = M + __log2f(S);
  }
}

__global__ __launch_bounds__(512) void fpacc_kernel(
    const unsigned short* __restrict__ H, const unsigned short* __restrict__ W2T,
    const float* __restrict__ b2, const float* __restrict__ T,
    float* __restrict__ partials, int n, int nPad) {
  __shared__ short8 ldsB[2048];   // 32 KB
  __shared__ float ldsBias[128];
  __shared__ float fp_w[8][128];  // 4 KB
  const int wave = threadIdx.x >> 6;
  const int lane = threadIdx.x & 63;
  const int lr = lane & 15, lg = lane >> 4;
  const int nRowBlk = nPad >> 8;
  const int rowBlk = blockIdx.x % nRowBlk;
  const int colBlk = blockIdx.x / nRowBlk;
  const int rowBase = rowBlk * 256 + wave * 32;
  const int colBase = colBlk * 128;

#pragma unroll
  for (int r = 0; r < 4; ++r) {
    const int p = r * 8 + wave;
    const int ct = p >> 2, q = p & 3;
    ldsB[p * 64 + lane] =
        *(const short8*)(W2T + (size_t)(colBase + ct * 16 + lr) * FEAT + (q * 4 + lg) * 8);
  }
  if (threadIdx.x < 128) ldsBias[threadIdx.x] = b2[colBase + threadIdx.x] * LOG2E;

  short8 a[2][4];
#pragma unroll
  for (int g = 0; g < 2; ++g)
#pragma unroll
    for (int kt = 0; kt < 4; ++kt)
      a[g][kt] = *(const short8*)(H + (size_t)(rowBase + g * 16 + lr) * FEAT + kt * 32 + lg * 8);
  float Tq[2][4];
#pragma unroll
  for (int g = 0; g < 2; ++g)
#pragma unroll
    for (int j = 0; j < 4; ++j) {
      const int row = rowBase + g * 16 + lg * 4 + j;
      Tq[g][j] = (row < n) ? T[row] : 1e30f;
    }
  __syncthreads();

#pragma unroll 4
  for (int ct = 0; ct < 8; ++ct) {
    short8 q0 = ldsB[(ct * 4 + 0) * 64 + lane];
    short8 q1 = ldsB[(ct * 4 + 1) * 64 + lane];
    short8 q2 = ldsB[(ct * 4 + 2) * 64 + lane];
    short8 q3 = ldsB[(ct * 4 + 3) * 64 + lane];
    f32x4 c0 = {0.f, 0.f, 0.f, 0.f};
    f32x4 c1 = {0.f, 0.f, 0.f, 0.f};
    c0 = mfma16(a[0][0], q0, c0);
    c1 = mfma16(a[1][0], q0, c1);
    c0 = mfma16(a[0][1], q1, c0);
    c1 = mfma16(a[1][1], q1, c1);
    c0 = mfma16(a[0][2], q2, c0);
    c1 = mfma16(a[1][2], q2, c1);
    c0 = mfma16(a[0][3], q3, c0);
    c1 = mfma16(a[1][3], q3, c1);
    const float bs = ldsBias[ct * 16 + lr];
    float p = exp2x(c0[0] + (bs - Tq[0][0])) + exp2x(c0[1] + (bs - Tq[0][1])) +
              exp2x(c0[2] + (bs - Tq[0][2])) + exp2x(c0[3] + (bs - Tq[0][3])) +
              exp2x(c1[0] + (bs - Tq[1][0])) + exp2x(c1[1] + (bs - Tq[1][1])) +
              exp2x(c1[2] + (bs - Tq[1][2])) + exp2x(c1[3] + (bs - Tq[1][3]));
    p += __shfl_xor(p, 16, 64);
    p += __shfl_xor(p, 32, 64);
    if (lg == 0) fp_w[wave][ct * 16 + lr] = p;
  }
  __syncthreads();
  if (threadIdx.x < 128) {
    float sum = 0.f;
#pragma unroll
    for (int w = 0; w < 8; ++w) sum += fp_w[w][threadIdx.x];
    partials[(size_t)rowBlk * FPL + colBase + threadIdx.x] += sum;
  }
}

__global__ void reduce_kernel(const float* __restrict__ partials, float* __restrict__ out, int nPart) {
  int c = blockIdx.x * 256 + threadIdx.x;
  if (c < FPL) {
    float s = 0.f;
    for (int p = 0; p < nPart; ++p) s += partials[(size_t)p * FPL + c];
    out[c] = s;
  }
}

extern "C" void kernel_launch(void* const* d_in, const int* in_sizes, int n_in,
                              void* d_out, int out_size, void* d_ws, size_t ws_size,
                              hipStream_t stream) {
  const float* atoms = (const float*)d_in[0];
  const float* W1 = (const float*)d_in[1];
  const float* b1 = (const float*)d_in[2];
  const float* W2 = (const float*)d_in[3];
  const float* b2 = (const float*)d_in[4];
  const int* esrc = (const int*)d_in[5];
  const int* edst = (const int*)d_in[6];
  const int nAtoms = in_sizes[0] / FEAT;
  const int nEdges = in_sizes[5];
  if (nAtoms <= 0) return;

  const int g2Blocks = (nAtoms + 255) / 256;
  const int nPad = g2Blocks * 256;
  const int g1Blocks = nPad / 64;
  const int nChunks = (nAtoms + 1023) / 1024;

  size_t off = 0;
  auto alloc = [&](size_t bytes) -> void* {
    void* p = (char*)d_ws + off;
    off += (bytes + 255) & ~(size_t)255;
    return p;
  };
  unsigned short* P = (unsigned short*)alloc((size_t)nPad * FEAT * 2);
  unsigned short* Q = (unsigned short*)alloc((size_t)nPad * FEAT * 2);
  unsigned short* W1T = (unsigned short*)alloc((size_t)FEAT * FEAT * 2);
  unsigned short* W2T = (unsigned short*)alloc((size_t)FEAT * FPL * 2);
  int* counts = (int*)alloc((size_t)nAtoms * 4);
  int* rank = (int*)alloc((size_t)nEdges * 4);
  int* rp = (int*)alloc(((size_t)nAtoms + 1) * 4);
  int* ex = (int*)alloc((size_t)nAtoms * 4);
  int* chunkSum = (int*)alloc((size_t)nChunks * 4);
  int* chunkOff = (int*)alloc((size_t)nChunks * 4);
  int* col = (int*)alloc((size_t)nEdges * 4);
  float* pm = (float*)alloc((size_t)16 * nPad * 4);
  float* ps = (float*)alloc((size_t)16 * nPad * 4);
  float* Trow = (float*)alloc((size_t)nPad * 4);
  float* partials = (float*)alloc((size_t)g2Blocks * FPL * 4);

  hipMemsetAsync(counts, 0, (size_t)nAtoms * 4, stream);
  hipMemsetAsync(partials, 0, (size_t)g2Blocks * FPL * 4, stream);
  hipMemsetAsync(P + (size_t)nAtoms * FEAT, 0, (size_t)(nPad - nAtoms) * FEAT * 2, stream);
  hipMemsetAsync(Q + (size_t)nAtoms * FEAT, 0, (size_t)(nPad - nAtoms) * FEAT * 2, stream);

  const int n2 = in_sizes[0] / 2;
  cvt_kernel<<<(n2 + 255) / 256, 256, 0, stream>>>(atoms, P, n2);
  cvtT_kernel<<<(FEAT * FEAT + 255) / 256, 256, 0, stream>>>(W1, W1T, FEAT, FEAT, 1.0f);
  cvtT_kernel<<<(FEAT * FPL + 255) / 256, 256, 0, stream>>>(W2, W2T, FEAT, FPL, LOG2E);
  countrank_kernel<<<(nEdges + 255) / 256, 256, 0, stream>>>(edst, counts, rank, nEdges);
  scan1_kernel<<<nChunks, 1024, 0, stream>>>(counts, ex, chunkSum, nAtoms);
  scan2_kernel<<<1, 1024, 0, stream>>>(chunkSum, chunkOff, nChunks);
  scan3_kernel<<<(nAtoms + 255) / 256, 256, 0, stream>>>(ex, chunkOff, chunkSum, rp, nAtoms, nChunks);
  fillp_kernel<<<1024, 256, 0, stream>>>(esrc, edst, rank, rp, col, nEdges, nAtoms);

  unsigned short* x = P;
  unsigned short* y = Q;
  for (int step = 0; step < 3; ++step) {
    gather_kernel<<<(nAtoms + 3) / 4, 256, 0, stream>>>(x, rp, col, y, nAtoms);
    gemm1_kernel<<<g1Blocks, 256, 0, stream>>>(y, W1T, b1, y, nAtoms);
    statT_kernel<<<g2Blocks * 16, 512, 0, stream>>>(y, W2T, b2, pm, ps, nPad);
    mergeT_kernel<<<(nPad + 255) / 256, 256, 0, stream>>>(pm, ps, Trow, nPad);
    fpacc_kernel<<<g2Blocks * 16, 512, 0, stream>>>(y, W2T, b2, Trow, partials, nAtoms, nPad);
    unsigned short* t = x; x = y; y = t;
  }
  reduce_kernel<<<(FPL + 255) / 256, 256, 0, stream>>>(partials, (float*)d_out, g2Blocks);
}